// Round 1
// baseline (2415.668 us; speedup 1.0000x reference)
//
#include <hip/hip_runtime.h>
#include <math.h>

#define NH 16
#define NKV 8
#define HDIM 128
#define SEQ 2048
#define DMODEL 2048

static constexpr float SM_SCALE = 0.08838834764831843f; // 128**-0.5 (double, rounded f32 at use)

// ---------------- per-row symmetric int8 fake quant-dequant ----------------
// one block per row; cols multiple of 4
__global__ __launch_bounds__(256) void row_qdq_k(const float* __restrict__ in,
                                                 float* __restrict__ out, int cols) {
    int row = blockIdx.x;
    const float4* x4 = (const float4*)(in + (size_t)row * cols);
    float4* y4 = (float4*)(out + (size_t)row * cols);
    int n4 = cols >> 2;
    int tid = threadIdx.x;
    float amax = 0.f;
    for (int c = tid; c < n4; c += 256) {
        float4 v = x4[c];
        amax = fmaxf(amax, fmaxf(fmaxf(fabsf(v.x), fabsf(v.y)),
                                 fmaxf(fabsf(v.z), fabsf(v.w))));
    }
#pragma unroll
    for (int m = 32; m; m >>= 1) amax = fmaxf(amax, __shfl_xor(amax, m));
    __shared__ float red[4];
    if ((tid & 63) == 0) red[tid >> 6] = amax;
    __syncthreads();
    float a = fmaxf(fmaxf(red[0], red[1]), fmaxf(red[2], red[3]));
    float s = fmaxf(a / 127.0f, 1e-8f);
    for (int c = tid; c < n4; c += 256) {
        float4 v = x4[c];
        float4 r;
        r.x = fminf(fmaxf(rintf(v.x / s), -127.f), 127.f) * s;
        r.y = fminf(fmaxf(rintf(v.y / s), -127.f), 127.f) * s;
        r.z = fminf(fmaxf(rintf(v.z / s), -127.f), 127.f) * s;
        r.w = fminf(fmaxf(rintf(v.w / s), -127.f), 127.f) * s;
        y4[c] = r;
    }
}

// ---------------- fp32 GEMM, C[M,N] = A[M,K] * B[N,K]^T ----------------
// 128x128 tile, BK=8, 256 threads, 8x8 per thread
__global__ __launch_bounds__(256) void gemm_nt(const float* __restrict__ A,
                                               const float* __restrict__ B,
                                               float* __restrict__ C,
                                               int M, int N, int K) {
    __shared__ float As[8][128];
    __shared__ float Bs[8][128];
    int tid = threadIdx.x;
    int tx = tid & 15, ty = tid >> 4;
    int m0 = blockIdx.y * 128, n0 = blockIdx.x * 128;
    int lr = tid >> 1;          // 0..127
    int lc = (tid & 1) << 2;    // 0 or 4
    const float* Ap = A + (size_t)(m0 + lr) * K + lc;
    const float* Bp = B + (size_t)(n0 + lr) * K + lc;
    float acc[8][8];
#pragma unroll
    for (int i = 0; i < 8; ++i)
#pragma unroll
        for (int j = 0; j < 8; ++j) acc[i][j] = 0.f;

    for (int k0 = 0; k0 < K; k0 += 8) {
        float4 av = *(const float4*)(Ap + k0);
        float4 bv = *(const float4*)(Bp + k0);
        __syncthreads();            // previous compute done before LDS overwrite
        As[lc + 0][lr] = av.x; As[lc + 1][lr] = av.y;
        As[lc + 2][lr] = av.z; As[lc + 3][lr] = av.w;
        Bs[lc + 0][lr] = bv.x; Bs[lc + 1][lr] = bv.y;
        Bs[lc + 2][lr] = bv.z; Bs[lc + 3][lr] = bv.w;
        __syncthreads();
#pragma unroll
        for (int kk = 0; kk < 8; ++kk) {
            float4 a0 = *(const float4*)&As[kk][ty * 8];
            float4 a1 = *(const float4*)&As[kk][ty * 8 + 4];
            float4 b0 = *(const float4*)&Bs[kk][tx * 8];
            float4 b1 = *(const float4*)&Bs[kk][tx * 8 + 4];
            float aa[8] = {a0.x, a0.y, a0.z, a0.w, a1.x, a1.y, a1.z, a1.w};
            float bb[8] = {b0.x, b0.y, b0.z, b0.w, b1.x, b1.y, b1.z, b1.w};
#pragma unroll
            for (int i = 0; i < 8; ++i)
#pragma unroll
                for (int j = 0; j < 8; ++j) acc[i][j] += aa[i] * bb[j];
        }
    }
#pragma unroll
    for (int i = 0; i < 8; ++i) {
        float* Cp = C + (size_t)(m0 + ty * 8 + i) * N + n0 + tx * 8;
        *(float4*)Cp = make_float4(acc[i][0], acc[i][1], acc[i][2], acc[i][3]);
        *(float4*)(Cp + 4) = make_float4(acc[i][4], acc[i][5], acc[i][6], acc[i][7]);
    }
}

// ---------------- rmsnorm + rope + qdq for q/k, qdq for v ----------------
// grid (SEQ, 32): y<16 -> q head, y<24 -> k head, else v head. 128 threads.
__global__ __launch_bounds__(128) void qkv_post_k(const float* __restrict__ q_lin,
        const float* __restrict__ k_lin, const float* __restrict__ v_lin,
        const float* __restrict__ qw, const float* __restrict__ kw,
        const int* __restrict__ pos_ids,
        float* __restrict__ q_dq, float* __restrict__ k_dq, float* __restrict__ v_dq) {
    int t = blockIdx.x;
    int hh = blockIdx.y;
    int d = threadIdx.x;
    __shared__ float xs[HDIM];
    __shared__ float red[2];
    float x;
    if (hh < NH)            x = q_lin[(size_t)t * DMODEL + hh * HDIM + d];
    else if (hh < NH + NKV) x = k_lin[(size_t)t * (NKV * HDIM) + (hh - NH) * HDIM + d];
    else                    x = v_lin[(size_t)t * (NKV * HDIM) + (hh - NH - NKV) * HDIM + d];

    if (hh < NH + NKV) {
        // rms norm (weights are inputs; multiply even though they are ones)
        float sq = x * x;
#pragma unroll
        for (int m = 32; m; m >>= 1) sq += __shfl_xor(sq, m);
        if ((d & 63) == 0) red[d >> 6] = sq;
        __syncthreads();
        float mv = (red[0] + red[1]) / 128.0f;
        float rs = 1.0f / sqrtf(mv + 1e-6f);
        x = (x * rs) * ((hh < NH) ? qw[d] : kw[d]);
        xs[d] = x;
        __syncthreads();
        float other = (d < 64) ? xs[d + 64] : xs[d - 64];
        int fi = d & 63;
        // inv_freq: ref computes 1/(1e6^(i/64)) in f32; double pow -> correctly rounded
        float pw = (float)pow(1.0e6, (double)fi / 64.0);
        float inv = 1.0f / pw;
        float fr = (float)pos_ids[t] * inv;
        float sn, c;
        sincosf(fr, &sn, &c);
        x = (d < 64) ? (x * c - other * sn) : (x * c + other * sn);
        __syncthreads();
    }
    // qdq over the 128-row
    float amax = fabsf(x);
#pragma unroll
    for (int m = 32; m; m >>= 1) amax = fmaxf(amax, __shfl_xor(amax, m));
    if ((d & 63) == 0) red[d >> 6] = amax;
    __syncthreads();
    float s = fmaxf(fmaxf(red[0], red[1]) / 127.0f, 1e-8f);
    float qv = fminf(fmaxf(rintf(x / s), -127.f), 127.f) * s;
    if (hh < NH)            q_dq[((size_t)hh * SEQ + t) * HDIM + d] = qv;
    else if (hh < NH + NKV) k_dq[((size_t)(hh - NH) * SEQ + t) * HDIM + d] = qv;
    else                    v_dq[((size_t)(hh - NH - NKV) * SEQ + t) * HDIM + d] = qv;
}

// ---------------- causal attention with quantized p, flash two-pass ----------------
#define QB 64
#define KB 32

// xor-swizzle float4 groups within a 128-float row (kills stride-512B bank conflict)
__device__ __forceinline__ int swz(int r, int c) {
    return r * HDIM + ((((c >> 2) ^ (r & 7)) << 2) | (c & 3));
}

__global__ __launch_bounds__(256) void attn_k(const float* __restrict__ q_dq,
        const float* __restrict__ k_dq, const float* __restrict__ v_dq,
        float* __restrict__ attn2) {
    __shared__ float qs[QB * HDIM];     // 32 KB, swizzled
    __shared__ float ksps[KB * HDIM];   // 16 KB, k tile (swizzled); re-used as p tile [QB][33]
    __shared__ float vs[KB * HDIM];     // 16 KB, swizzled
    int qb = blockIdx.x;
    int h = blockIdx.y;
    int kvh = h >> 1;                   // GQA: jnp.repeat(k,2,axis=1) -> head h uses kv h/2
    int q0 = qb * QB;
    int tid = threadIdx.x;
    int tx = tid & 15, ty = tid >> 4;

    {   // stage q tile
        const float* src = q_dq + ((size_t)h * SEQ + q0) * HDIM;
#pragma unroll
        for (int i = 0; i < 8; ++i) {
            int f4 = i * 256 + tid;
            int r = f4 >> 5, c = (f4 & 31) << 2;
            *(float4*)&qs[swz(r, c)] = *(const float4*)(src + r * HDIM + c);
        }
    }

    float m_run[4], z_run[4];
#pragma unroll
    for (int i = 0; i < 4; ++i) { m_run[i] = -1e30f; z_run[i] = 0.f; }

    int nkb = 2 * qb + 2;
    const float* kbase = k_dq + (size_t)kvh * SEQ * HDIM;
    const float* vbase = v_dq + (size_t)kvh * SEQ * HDIM;

    // ---- pass 1: row max + Z ----
    for (int kb = 0; kb < nkb; ++kb) {
        int k0 = kb * KB;
        __syncthreads();
#pragma unroll
        for (int i = 0; i < 4; ++i) {
            int f4 = i * 256 + tid;
            int r = f4 >> 5, c = (f4 & 31) << 2;
            *(float4*)&ksps[swz(r, c)] = *(const float4*)(kbase + (size_t)(k0 + r) * HDIM + c);
        }
        __syncthreads();
        float sc[4][2];
#pragma unroll
        for (int i = 0; i < 4; ++i) { sc[i][0] = 0.f; sc[i][1] = 0.f; }
        for (int dd = 0; dd < HDIM; dd += 4) {
            float4 kv0 = *(const float4*)&ksps[swz(tx * 2, dd)];
            float4 kv1 = *(const float4*)&ksps[swz(tx * 2 + 1, dd)];
#pragma unroll
            for (int i = 0; i < 4; ++i) {
                float4 qv = *(const float4*)&qs[swz(ty * 4 + i, dd)];
                sc[i][0] += qv.x * kv0.x + qv.y * kv0.y + qv.z * kv0.z + qv.w * kv0.w;
                sc[i][1] += qv.x * kv1.x + qv.y * kv1.y + qv.z * kv1.z + qv.w * kv1.w;
            }
        }
#pragma unroll
        for (int i = 0; i < 4; ++i) {
            int qt = q0 + ty * 4 + i;
            float s0 = (k0 + tx * 2     <= qt) ? sc[i][0] * SM_SCALE : -1e30f;
            float s1 = (k0 + tx * 2 + 1 <= qt) ? sc[i][1] * SM_SCALE : -1e30f;
            float mt = fmaxf(s0, s1);
#pragma unroll
            for (int m = 8; m; m >>= 1) mt = fmaxf(mt, __shfl_xor(mt, m));
            float mn = fmaxf(m_run[i], mt);
            float zt = 0.f;
            if (s0 > -1e29f) zt += expf(s0 - mn);
            if (s1 > -1e29f) zt += expf(s1 - mn);
#pragma unroll
            for (int m = 8; m; m >>= 1) zt += __shfl_xor(zt, m);
            z_run[i] = z_run[i] * expf(m_run[i] - mn) + zt;
            m_run[i] = mn;
        }
    }

    // p-row quant scale: max of softmax row is exactly fl(1/Z)
    float sp[4];
#pragma unroll
    for (int i = 0; i < 4; ++i) {
        float pmax = 1.0f / z_run[i];
        sp[i] = fmaxf(pmax / 127.0f, 1e-8f);
    }

    float acc[4][8];
#pragma unroll
    for (int i = 0; i < 4; ++i)
#pragma unroll
        for (int j = 0; j < 8; ++j) acc[i][j] = 0.f;

    // ---- pass 2: recompute scores, quantize p, accumulate PV ----
    for (int kb = 0; kb < nkb; ++kb) {
        int k0 = kb * KB;
        __syncthreads();    // previous PV (reads vs/ps) done
#pragma unroll
        for (int i = 0; i < 4; ++i) {
            int f4 = i * 256 + tid;
            int r = f4 >> 5, c = (f4 & 31) << 2;
            *(float4*)&ksps[swz(r, c)] = *(const float4*)(kbase + (size_t)(k0 + r) * HDIM + c);
            *(float4*)&vs[swz(r, c)]   = *(const float4*)(vbase + (size_t)(k0 + r) * HDIM + c);
        }
        __syncthreads();
        float sc[4][2];
#pragma unroll
        for (int i = 0; i < 4; ++i) { sc[i][0] = 0.f; sc[i][1] = 0.f; }
        for (int dd = 0; dd < HDIM; dd += 4) {
            float4 kv0 = *(const float4*)&ksps[swz(tx * 2, dd)];
            float4 kv1 = *(const float4*)&ksps[swz(tx * 2 + 1, dd)];
#pragma unroll
            for (int i = 0; i < 4; ++i) {
                float4 qv = *(const float4*)&qs[swz(ty * 4 + i, dd)];
                sc[i][0] += qv.x * kv0.x + qv.y * kv0.y + qv.z * kv0.z + qv.w * kv0.w;
                sc[i][1] += qv.x * kv1.x + qv.y * kv1.y + qv.z * kv1.z + qv.w * kv1.w;
            }
        }
        __syncthreads();    // scores done reading k tile before p overwrites it
#pragma unroll
        for (int i = 0; i < 4; ++i) {
            int qt = q0 + ty * 4 + i;
#pragma unroll
            for (int j = 0; j < 2; ++j) {
                int kt = k0 + tx * 2 + j;
                float pd = 0.f;
                if (kt <= qt) {
                    float sv = sc[i][j] * SM_SCALE;
                    float p = expf(sv - m_run[i]) / z_run[i];
                    float pq = fminf(fmaxf(rintf(p / sp[i]), -127.f), 127.f);
                    pd = pq * sp[i];
                }
                ksps[(ty * 4 + i) * 33 + (tx * 2 + j)] = pd;   // p tile [64][33], fits in 16 KB
            }
        }
        __syncthreads();
        // PV: acc[i][0..7] += sum_kk p[m][kk] * v[kk][tx*8..]
        for (int kk = 0; kk < KB; ++kk) {
            float4 v0 = *(const float4*)&vs[swz(kk, tx * 8)];
            float4 v1 = *(const float4*)&vs[swz(kk, tx * 8 + 4)];
#pragma unroll
            for (int i = 0; i < 4; ++i) {
                float pv = ksps[(ty * 4 + i) * 33 + kk];
                acc[i][0] += pv * v0.x; acc[i][1] += pv * v0.y;
                acc[i][2] += pv * v0.z; acc[i][3] += pv * v0.w;
                acc[i][4] += pv * v1.x; acc[i][5] += pv * v1.y;
                acc[i][6] += pv * v1.z; acc[i][7] += pv * v1.w;
            }
        }
    }
#pragma unroll
    for (int i = 0; i < 4; ++i) {
        float* dst = attn2 + (size_t)(q0 + ty * 4 + i) * DMODEL + h * HDIM + tx * 8;
        *(float4*)dst = make_float4(acc[i][0], acc[i][1], acc[i][2], acc[i][3]);
        *(float4*)(dst + 4) = make_float4(acc[i][4], acc[i][5], acc[i][6], acc[i][7]);
    }
}

extern "C" void kernel_launch(void* const* d_in, const int* in_sizes, int n_in,
                              void* d_out, int out_size, void* d_ws, size_t ws_size,
                              hipStream_t stream) {
    (void)in_sizes; (void)n_in; (void)out_size; (void)ws_size;
    const float* hidden = (const float*)d_in[0];
    const float* Wq = (const float*)d_in[1];
    const float* Wk = (const float*)d_in[2];
    const float* Wv = (const float*)d_in[3];
    const float* Wo = (const float*)d_in[4];
    const float* qw = (const float*)d_in[5];
    const float* kw = (const float*)d_in[6];
    const int* pos = (const int*)d_in[7];
    float* out = (float*)d_out;
    float* ws = (float*)d_ws;

    const size_t M4 = 4194304;          // 4M floats = 16 MB
    float* xq    = ws;                  // [S, D]
    float* wqd   = ws + M4;             // [2048, 2048]
    float* wkd   = ws + 2 * M4;         // [1024, 2048]
    float* wvd   = ws + 2 * M4 + M4 / 2;
    float* wod   = ws + 3 * M4;         // [2048, 2048]
    float* q_lin = ws + 4 * M4;         // [S, 2048]
    float* k_lin = ws + 5 * M4;         // [S, 1024]
    float* v_lin = ws + 5 * M4 + M4 / 2;
    // buffer reuse (lifetimes disjoint):
    float* q_dq  = wqd;                 // [NH][S][128]
    float* k_dq  = wkd;                 // [NKV][S][128]
    float* v_dq  = wvd;                 // [NKV][S][128]
    float* attn2 = q_lin;               // [S, 2048]
    float* a_dq  = xq;                  // [S, 2048]

    row_qdq_k<<<2048, 256, 0, stream>>>(hidden, xq, 2048);
    row_qdq_k<<<2048, 256, 0, stream>>>(Wq, wqd, 2048);
    row_qdq_k<<<1024, 256, 0, stream>>>(Wk, wkd, 2048);
    row_qdq_k<<<1024, 256, 0, stream>>>(Wv, wvd, 2048);
    row_qdq_k<<<2048, 256, 0, stream>>>(Wo, wod, 2048);

    gemm_nt<<<dim3(16, 16), 256, 0, stream>>>(xq, wqd, q_lin, 2048, 2048, 2048);
    gemm_nt<<<dim3(8, 16), 256, 0, stream>>>(xq, wkd, k_lin, 2048, 1024, 2048);
    gemm_nt<<<dim3(8, 16), 256, 0, stream>>>(xq, wvd, v_lin, 2048, 1024, 2048);

    qkv_post_k<<<dim3(2048, 32), 128, 0, stream>>>(q_lin, k_lin, v_lin, qw, kw, pos,
                                                   q_dq, k_dq, v_dq);

    attn_k<<<dim3(32, 16), 256, 0, stream>>>(q_dq, k_dq, v_dq, attn2);

    row_qdq_k<<<2048, 256, 0, stream>>>(attn2, a_dq, 2048);
    gemm_nt<<<dim3(16, 16), 256, 0, stream>>>(a_dq, wod, out, 2048, 2048, 2048);
}

// Round 2
// 419.913 us; speedup vs baseline: 5.7528x; 5.7528x over previous
//
#include <hip/hip_runtime.h>
#include <math.h>

#define NH 16
#define NKV 8
#define HDIM 128
#define SEQ 2048
#define DMODEL 2048

typedef int   v4i __attribute__((ext_vector_type(4)));
typedef float v4f __attribute__((ext_vector_type(4)));
typedef __bf16 v8bf __attribute__((ext_vector_type(8)));

static constexpr float SM_SCALE = 0.08838834764831843f; // 128**-0.5

#define GLOBP(p) (__attribute__((address_space(1))) void*)(p)
#define LDSP(p)  (__attribute__((address_space(3))) void*)(p)
// 16-byte async global->LDS: HW writes lds_base + lane*16; lds_base must be wave-uniform.
#define ASYNC16(g, l) __builtin_amdgcn_global_load_lds(GLOBP(g), LDSP(l), 16, 0, 0)

// ---------------- per-row symmetric int8 quant: int8 out + scale ----------------
__global__ __launch_bounds__(256) void row_quant_k(const float* __restrict__ in,
        signed char* __restrict__ out, float* __restrict__ scale, int cols) {
    int row = blockIdx.x;
    const float4* x4 = (const float4*)(in + (size_t)row * cols);
    unsigned int* op = (unsigned int*)(out + (size_t)row * cols);
    int n4 = cols >> 2;
    int tid = threadIdx.x;
    float amax = 0.f;
    for (int c = tid; c < n4; c += 256) {
        float4 v = x4[c];
        amax = fmaxf(amax, fmaxf(fmaxf(fabsf(v.x), fabsf(v.y)),
                                 fmaxf(fabsf(v.z), fabsf(v.w))));
    }
#pragma unroll
    for (int m = 32; m; m >>= 1) amax = fmaxf(amax, __shfl_xor(amax, m));
    __shared__ float red[4];
    if ((tid & 63) == 0) red[tid >> 6] = amax;
    __syncthreads();
    float a = fmaxf(fmaxf(red[0], red[1]), fmaxf(red[2], red[3]));
    float s = fmaxf(a / 127.0f, 1e-8f);
    if (tid == 0) scale[row] = s;
    for (int c = tid; c < n4; c += 256) {
        float4 v = x4[c];
        int b0 = (int)fminf(fmaxf(rintf(v.x / s), -127.f), 127.f);
        int b1 = (int)fminf(fmaxf(rintf(v.y / s), -127.f), 127.f);
        int b2 = (int)fminf(fmaxf(rintf(v.z / s), -127.f), 127.f);
        int b3 = (int)fminf(fmaxf(rintf(v.w / s), -127.f), 127.f);
        op[c] = (b0 & 255) | ((b1 & 255) << 8) | ((b2 & 255) << 16) | ((b3 & 255) << 24);
    }
}

// ---------------- int8 GEMM: C[m,n] = sa[m]*sb[n]*sum_k qa[m,k]*qb[n,k] ----------------
// 128x128 tile, BK=64, 256 threads (4 waves, 2x2), mfma_i32_16x16x64_i8.
// LDS fragment-linear: frag f = 16 rows x 64 k-bytes at [f*1024 + lane*16],
// lane l <-> (row = l&15, kbytes = (l>>4)*16) -> ds_read_b128 is lane-linear (conflict-free).
__global__ __launch_bounds__(256) void gemm_i8_k(const signed char* __restrict__ A,
        const float* __restrict__ sa, const signed char* __restrict__ B,
        const float* __restrict__ sb, float* __restrict__ C, int M, int N, int K) {
    __shared__ __align__(16) signed char lsA[8192];
    __shared__ __align__(16) signed char lsB[8192];
    int tid = threadIdx.x;
    int w = tid >> 6, l = tid & 63;
    int wr = w >> 1, wc = w & 1;
    int lrow = l & 15, lk = (l >> 4) * 16;
    int m0 = blockIdx.y * 128, n0 = blockIdx.x * 128;
    v4i acc[4][4];
#pragma unroll
    for (int i = 0; i < 4; ++i)
#pragma unroll
        for (int j = 0; j < 4; ++j) acc[i][j] = (v4i){0, 0, 0, 0};

    for (int k0 = 0; k0 < K; k0 += 64) {
        __syncthreads();
#pragma unroll
        for (int a = 0; a < 2; ++a) {
            int f = a * 4 + w;
            ASYNC16(A + (size_t)(m0 + f * 16 + lrow) * K + k0 + lk, lsA + f * 1024);
            ASYNC16(B + (size_t)(n0 + f * 16 + lrow) * K + k0 + lk, lsB + f * 1024);
        }
        __syncthreads();
        v4i af[4], bf[4];
#pragma unroll
        for (int i = 0; i < 4; ++i) af[i] = *(const v4i*)(lsA + (wr * 4 + i) * 1024 + l * 16);
#pragma unroll
        for (int j = 0; j < 4; ++j) bf[j] = *(const v4i*)(lsB + (wc * 4 + j) * 1024 + l * 16);
#pragma unroll
        for (int i = 0; i < 4; ++i)
#pragma unroll
            for (int j = 0; j < 4; ++j)
                acc[i][j] = __builtin_amdgcn_mfma_i32_16x16x64_i8(af[i], bf[j], acc[i][j], 0, 0, 0);
    }
    int r0 = m0 + wr * 64, c0 = n0 + wc * 64;
    int lg = l >> 4;
    float sbv[4];
#pragma unroll
    for (int j = 0; j < 4; ++j) sbv[j] = sb[c0 + j * 16 + lrow];
#pragma unroll
    for (int i = 0; i < 4; ++i) {
        float4 s4 = *(const float4*)(sa + r0 + i * 16 + lg * 4);
        float sav[4] = {s4.x, s4.y, s4.z, s4.w};
#pragma unroll
        for (int j = 0; j < 4; ++j) {
#pragma unroll
            for (int reg = 0; reg < 4; ++reg) {
                int r = r0 + i * 16 + lg * 4 + reg;
                C[(size_t)r * N + c0 + j * 16 + lrow] = (float)acc[i][j][reg] * (sav[reg] * sbv[j]);
            }
        }
    }
}

// ---------------- rmsnorm + rope; q/k -> int8 + scale, v -> dequantized fp32 ----------------
__global__ __launch_bounds__(128) void qkv_post_k(const float* __restrict__ q_lin,
        const float* __restrict__ k_lin, const float* __restrict__ v_lin,
        const float* __restrict__ qw, const float* __restrict__ kw,
        const int* __restrict__ pos_ids,
        signed char* __restrict__ q_i8, float* __restrict__ sq,
        signed char* __restrict__ k_i8, float* __restrict__ sk,
        float* __restrict__ v_dq) {
    int t = blockIdx.x;
    int hh = blockIdx.y;
    int d = threadIdx.x;
    __shared__ float xs[HDIM];
    __shared__ float red[2];
    float x;
    if (hh < NH)            x = q_lin[(size_t)t * DMODEL + hh * HDIM + d];
    else if (hh < NH + NKV) x = k_lin[(size_t)t * (NKV * HDIM) + (hh - NH) * HDIM + d];
    else                    x = v_lin[(size_t)t * (NKV * HDIM) + (hh - NH - NKV) * HDIM + d];

    if (hh < NH + NKV) {
        float sqv = x * x;
#pragma unroll
        for (int m = 32; m; m >>= 1) sqv += __shfl_xor(sqv, m);
        if ((d & 63) == 0) red[d >> 6] = sqv;
        __syncthreads();
        float mv = (red[0] + red[1]) / 128.0f;
        float rs = 1.0f / sqrtf(mv + 1e-6f);
        x = (x * rs) * ((hh < NH) ? qw[d] : kw[d]);
        xs[d] = x;
        __syncthreads();
        float other = (d < 64) ? xs[d + 64] : xs[d - 64];
        int fi = d & 63;
        float pw = (float)pow(1.0e6, (double)fi / 64.0);
        float inv = 1.0f / pw;
        float fr = (float)pos_ids[t] * inv;
        float sn, c;
        sincosf(fr, &sn, &c);
        x = (d < 64) ? (x * c - other * sn) : (x * c + other * sn);
        __syncthreads();
    }
    float amax = fabsf(x);
#pragma unroll
    for (int m = 32; m; m >>= 1) amax = fmaxf(amax, __shfl_xor(amax, m));
    if ((d & 63) == 0) red[d >> 6] = amax;
    __syncthreads();
    float s = fmaxf(fmaxf(red[0], red[1]) / 127.0f, 1e-8f);
    float qf = fminf(fmaxf(rintf(x / s), -127.f), 127.f);
    if (hh < NH) {
        q_i8[((size_t)hh * SEQ + t) * HDIM + d] = (signed char)(int)qf;
        if (d == 0) sq[hh * SEQ + t] = s;
    } else if (hh < NH + NKV) {
        k_i8[((size_t)(hh - NH) * SEQ + t) * HDIM + d] = (signed char)(int)qf;
        if (d == 0) sk[(hh - NH) * SEQ + t] = s;
    } else {
        v_dq[((size_t)(hh - NH - NKV) * SEQ + t) * HDIM + d] = qf * s;
    }
}

// ---------------- bf16 helpers ----------------
__device__ __forceinline__ unsigned short f2bf(float x) {
    unsigned int u = __float_as_uint(x);
    return (unsigned short)((u + 0x7fffu + ((u >> 16) & 1u)) >> 16);
}
__device__ __forceinline__ float bf2f(unsigned short h) {
    return __uint_as_float(((unsigned int)h) << 16);
}

// ---------------- V transpose + bf16 split: v_dq[kv][t][d] -> vt_hi/vt_lo[kv][d][t] ----------------
__global__ __launch_bounds__(256) void vt_split_k(const float* __restrict__ v_dq,
        unsigned short* __restrict__ vt_hi, unsigned short* __restrict__ vt_lo) {
    int kv = blockIdx.y, t0 = blockIdx.x * 64;
    __shared__ float tile[64][132];
    int tid = threadIdx.x;
    const float* src = v_dq + ((size_t)kv * SEQ + t0) * HDIM;
#pragma unroll
    for (int i = 0; i < 8; ++i) {
        int f4 = i * 256 + tid;
        int r = f4 >> 5, c = (f4 & 31) << 2;
        float4 v = *(const float4*)(src + r * HDIM + c);
        tile[r][c] = v.x; tile[r][c + 1] = v.y; tile[r][c + 2] = v.z; tile[r][c + 3] = v.w;
    }
    __syncthreads();
    int d = tid >> 1, th = (tid & 1) * 32;
    size_t obase = ((size_t)kv * HDIM + d) * SEQ + t0 + th;
#pragma unroll
    for (int j = 0; j < 32; j += 2) {
        float a = tile[th + j][d], b = tile[th + j + 1][d];
        unsigned short ah = f2bf(a), bh = f2bf(b);
        unsigned short al = f2bf(a - bf2f(ah)), bl = f2bf(b - bf2f(bh));
        *(unsigned int*)(vt_hi + obase + j) = (unsigned int)ah | ((unsigned int)bh << 16);
        *(unsigned int*)(vt_lo + obase + j) = (unsigned int)al | ((unsigned int)bl << 16);
    }
}

// ---------------- attention: int8-MFMA QK^T, fp32 softmax, bf16-split-MFMA PV ----------------
// Block: 256 thr (4 waves), QB=64 q-rows (wave w owns rows w*16..+16), KB=64.
__global__ __launch_bounds__(256) void attn_k(const signed char* __restrict__ q_i8,
        const float* __restrict__ sq, const signed char* __restrict__ k_i8,
        const float* __restrict__ sk, const unsigned short* __restrict__ vt_hi,
        const unsigned short* __restrict__ vt_lo, float* __restrict__ attn2) {
    __shared__ __align__(16) signed char klds[8192];     // 8 frags (j,kk)
    __shared__ __align__(16) unsigned short vlds[16384]; // 32 frags (split,jd,kk2)
    __shared__ __align__(16) unsigned short plds[4096];  // 8 frags (w,kk2)
    int qb = blockIdx.x, h = blockIdx.y, kvh = h >> 1;
    int q0 = qb * 64;
    int tid = threadIdx.x, w = tid >> 6, l = tid & 63;
    int lrow = l & 15, lg = l >> 4;

    const signed char* qrow = q_i8 + ((size_t)h * SEQ + q0 + w * 16 + lrow) * HDIM + lg * 16;
    v4i qf0 = *(const v4i*)(qrow);
    v4i qf1 = *(const v4i*)(qrow + 64);
    float4 s4 = *(const float4*)(sq + (size_t)h * SEQ + q0 + w * 16 + lg * 4);
    float sqr[4] = {s4.x, s4.y, s4.z, s4.w};

    float m_run[4], z_run[4];
#pragma unroll
    for (int r = 0; r < 4; ++r) { m_run[r] = -1e30f; z_run[r] = 0.f; }

    int nkb = qb + 1;
    const signed char* kbase = k_i8 + (size_t)kvh * SEQ * HDIM;
    const float* skb = sk + (size_t)kvh * SEQ;
    const unsigned short* vhb = vt_hi + (size_t)kvh * HDIM * SEQ;
    const unsigned short* vlb = vt_lo + (size_t)kvh * HDIM * SEQ;

    // ---- pass 1: running max + Z ----
    for (int kb = 0; kb < nkb; ++kb) {
        int k0 = kb * 64;
        __syncthreads();
#pragma unroll
        for (int a = 0; a < 2; ++a) {
            int fk = a * 4 + w, j = fk >> 1, kk = fk & 1;
            ASYNC16(kbase + (size_t)(k0 + j * 16 + lrow) * HDIM + kk * 64 + lg * 16,
                    klds + fk * 1024);
        }
        __syncthreads();
        v4i sci[4];
#pragma unroll
        for (int j = 0; j < 4; ++j) {
            v4i z = {0, 0, 0, 0};
            v4i t0 = __builtin_amdgcn_mfma_i32_16x16x64_i8(qf0, *(const v4i*)(klds + (j * 2) * 1024 + l * 16), z, 0, 0, 0);
            sci[j] = __builtin_amdgcn_mfma_i32_16x16x64_i8(qf1, *(const v4i*)(klds + (j * 2 + 1) * 1024 + l * 16), t0, 0, 0, 0);
        }
        float skc[4];
#pragma unroll
        for (int j = 0; j < 4; ++j) skc[j] = skb[k0 + j * 16 + lrow];
#pragma unroll
        for (int reg = 0; reg < 4; ++reg) {
            int r = q0 + w * 16 + lg * 4 + reg;
            float s[4];
#pragma unroll
            for (int j = 0; j < 4; ++j) {
                float sv = ((float)sci[j][reg] * (sqr[reg] * skc[j])) * SM_SCALE;
                s[j] = (k0 + j * 16 + lrow <= r) ? sv : -1e30f;
            }
            float mt = fmaxf(fmaxf(s[0], s[1]), fmaxf(s[2], s[3]));
#pragma unroll
            for (int m = 1; m <= 8; m <<= 1) mt = fmaxf(mt, __shfl_xor(mt, m));
            float mn = fmaxf(m_run[reg], mt);
            float zt = 0.f;
#pragma unroll
            for (int j = 0; j < 4; ++j) zt += __expf(s[j] - mn);
#pragma unroll
            for (int m = 1; m <= 8; m <<= 1) zt += __shfl_xor(zt, m);
            z_run[reg] = z_run[reg] * __expf(m_run[reg] - mn) + zt;
            m_run[reg] = mn;
        }
    }

    float zinv[4], spv[4], rsp[4];
#pragma unroll
    for (int r = 0; r < 4; ++r) {
        zinv[r] = 1.0f / z_run[r];               // = ref's max softmax element fl(1/Z)
        spv[r] = fmaxf(zinv[r] / 127.0f, 1e-8f);
        rsp[r] = 1.0f / spv[r];
    }

    v4f acco[8];
#pragma unroll
    for (int jd = 0; jd < 8; ++jd) acco[jd] = (v4f){0.f, 0.f, 0.f, 0.f};

    // ---- pass 2: scores -> int-quantized p -> PV ----
    for (int kb = 0; kb < nkb; ++kb) {
        int k0 = kb * 64;
        __syncthreads();
#pragma unroll
        for (int a = 0; a < 2; ++a) {
            int fk = a * 4 + w, j = fk >> 1, kk = fk & 1;
            ASYNC16(kbase + (size_t)(k0 + j * 16 + lrow) * HDIM + kk * 64 + lg * 16,
                    klds + fk * 1024);
        }
#pragma unroll
        for (int a = 0; a < 8; ++a) {
            int fv = a * 4 + w;
            int sp_ = fv >> 4, jd = (fv >> 1) & 7, kk2 = fv & 1;
            const unsigned short* vsrc = (sp_ ? vlb : vhb) +
                (size_t)(jd * 16 + lrow) * SEQ + k0 + kk2 * 32 + lg * 8;
            ASYNC16(vsrc, vlds + fv * 512);
        }
        __syncthreads();
        v4i sci[4];
#pragma unroll
        for (int j = 0; j < 4; ++j) {
            v4i z = {0, 0, 0, 0};
            v4i t0 = __builtin_amdgcn_mfma_i32_16x16x64_i8(qf0, *(const v4i*)(klds + (j * 2) * 1024 + l * 16), z, 0, 0, 0);
            sci[j] = __builtin_amdgcn_mfma_i32_16x16x64_i8(qf1, *(const v4i*)(klds + (j * 2 + 1) * 1024 + l * 16), t0, 0, 0, 0);
        }
        float skc[4];
#pragma unroll
        for (int j = 0; j < 4; ++j) skc[j] = skb[k0 + j * 16 + lrow];
#pragma unroll
        for (int reg = 0; reg < 4; ++reg) {
            int rq = lg * 4 + reg;
            int r = q0 + w * 16 + rq;
#pragma unroll
            for (int j = 0; j < 4; ++j) {
                int c = j * 16 + lrow;
                float pd = 0.f;
                if (k0 + c <= r) {
                    float sv = ((float)sci[j][reg] * (sqr[reg] * skc[j])) * SM_SCALE;
                    float p = __expf(sv - m_run[reg]) * zinv[reg];
                    pd = fminf(rintf(p * rsp[reg]), 127.f);   // int value of quantized p
                }
                // fragment-linear P: element (rq, c) -> frag (w*2 + c>>5), lane (rq + 16*((c>>3)&3)), half-word c&7
                plds[(w * 2 + (c >> 5)) * 512 + (rq + 16 * ((c >> 3) & 3)) * 8 + (c & 7)] =
                    (unsigned short)(__float_as_uint(pd) >> 16);  // exact bf16 of small int
            }
        }
        __syncthreads();
        v8bf pf0 = *(const v8bf*)(plds + (w * 2 + 0) * 512 + l * 8);
        v8bf pf1 = *(const v8bf*)(plds + (w * 2 + 1) * 512 + l * 8);
#pragma unroll
        for (int jd = 0; jd < 8; ++jd) {
            v8bf vh0 = *(const v8bf*)(vlds + (jd * 2 + 0) * 512 + l * 8);
            v8bf vh1 = *(const v8bf*)(vlds + (jd * 2 + 1) * 512 + l * 8);
            v8bf vl0 = *(const v8bf*)(vlds + (16 + jd * 2 + 0) * 512 + l * 8);
            v8bf vl1 = *(const v8bf*)(vlds + (16 + jd * 2 + 1) * 512 + l * 8);
            v4f t = acco[jd];
            t = __builtin_amdgcn_mfma_f32_16x16x32_bf16(pf0, vh0, t, 0, 0, 0);
            t = __builtin_amdgcn_mfma_f32_16x16x32_bf16(pf1, vh1, t, 0, 0, 0);
            t = __builtin_amdgcn_mfma_f32_16x16x32_bf16(pf0, vl0, t, 0, 0, 0);
            t = __builtin_amdgcn_mfma_f32_16x16x32_bf16(pf1, vl1, t, 0, 0, 0);
            acco[jd] = t;
        }
    }
#pragma unroll
    for (int jd = 0; jd < 8; ++jd) {
#pragma unroll
        for (int reg = 0; reg < 4; ++reg) {
            int r = q0 + w * 16 + lg * 4 + reg;
            attn2[(size_t)r * DMODEL + h * HDIM + jd * 16 + lrow] = acco[jd][reg] * spv[reg];
        }
    }
}

extern "C" void kernel_launch(void* const* d_in, const int* in_sizes, int n_in,
                              void* d_out, int out_size, void* d_ws, size_t ws_size,
                              hipStream_t stream) {
    (void)in_sizes; (void)n_in; (void)out_size; (void)ws_size;
    const float* hidden = (const float*)d_in[0];
    const float* Wq = (const float*)d_in[1];
    const float* Wk = (const float*)d_in[2];
    const float* Wv = (const float*)d_in[3];
    const float* Wo = (const float*)d_in[4];
    const float* qw = (const float*)d_in[5];
    const float* kw = (const float*)d_in[6];
    const int* pos = (const int*)d_in[7];
    float* out = (float*)d_out;
    char* ws = (char*)d_ws;

    const size_t MB = 1024 * 1024;
    signed char* x_i8  = (signed char*)(ws);            // 4 MB
    signed char* wq_i8 = (signed char*)(ws + 4 * MB);   // 4 MB
    signed char* wk_i8 = (signed char*)(ws + 8 * MB);   // 2 MB
    signed char* wv_i8 = (signed char*)(ws + 10 * MB);  // 2 MB
    signed char* wo_i8 = (signed char*)(ws + 12 * MB);  // 4 MB
    signed char* q_i8  = (signed char*)(ws + 16 * MB);  // 4 MB
    signed char* k_i8  = (signed char*)(ws + 20 * MB);  // 2 MB
    float* sx  = (float*)(ws + 22 * MB);                // scales block
    float* swq = sx + 2048;
    float* swk = swq + 2048;
    float* swv = swk + 1024;
    float* swo = swv + 1024;
    float* sq  = swo + 2048;                            // 16*2048
    float* sk  = sq + NH * SEQ;                         // 8*2048
    float* sa  = sk + NKV * SEQ;                        // 2048
    float* q_lin = (float*)(ws + 24 * MB);              // 16 MB
    float* k_lin = (float*)(ws + 40 * MB);              // 8 MB
    float* v_lin = (float*)(ws + 48 * MB);              // 8 MB (dead after qkv_post)
    unsigned short* vt_hi = (unsigned short*)(ws + 48 * MB);       // 4 MB (aliases v_lin)
    unsigned short* vt_lo = (unsigned short*)(ws + 52 * MB);       // 4 MB
    float* v_dq = (float*)(ws + 56 * MB);               // 8 MB
    float* attn2 = q_lin;                               // q_lin dead after qkv_post
    signed char* a_i8 = x_i8;                           // x_i8 dead after QKV GEMMs

    row_quant_k<<<2048, 256, 0, stream>>>(hidden, x_i8, sx, 2048);
    row_quant_k<<<2048, 256, 0, stream>>>(Wq, wq_i8, swq, 2048);
    row_quant_k<<<1024, 256, 0, stream>>>(Wk, wk_i8, swk, 2048);
    row_quant_k<<<1024, 256, 0, stream>>>(Wv, wv_i8, swv, 2048);
    row_quant_k<<<2048, 256, 0, stream>>>(Wo, wo_i8, swo, 2048);

    gemm_i8_k<<<dim3(16, 16), 256, 0, stream>>>(x_i8, sx, wq_i8, swq, q_lin, 2048, 2048, 2048);
    gemm_i8_k<<<dim3(8, 16), 256, 0, stream>>>(x_i8, sx, wk_i8, swk, k_lin, 2048, 1024, 2048);
    gemm_i8_k<<<dim3(8, 16), 256, 0, stream>>>(x_i8, sx, wv_i8, swv, v_lin, 2048, 1024, 2048);

    qkv_post_k<<<dim3(2048, 32), 128, 0, stream>>>(q_lin, k_lin, v_lin, qw, kw, pos,
                                                   q_i8, sq, k_i8, sk, v_dq);
    vt_split_k<<<dim3(32, 8), 256, 0, stream>>>(v_dq, vt_hi, vt_lo);

    attn_k<<<dim3(32, 16), 256, 0, stream>>>(q_i8, sq, k_i8, sk, vt_hi, vt_lo, attn2);

    row_quant_k<<<2048, 256, 0, stream>>>(attn2, a_i8, sa, 2048);
    gemm_i8_k<<<dim3(16, 16), 256, 0, stream>>>(a_i8, sa, wo_i8, swo, out, 2048, 2048, 2048);
}

// Round 3
// 402.471 us; speedup vs baseline: 6.0021x; 1.0433x over previous
//
#include <hip/hip_runtime.h>
#include <math.h>

#define NH 16
#define NKV 8
#define HDIM 128
#define SEQ 2048
#define DMODEL 2048

typedef int   v4i __attribute__((ext_vector_type(4)));
typedef float v4f __attribute__((ext_vector_type(4)));
typedef __bf16 v8bf __attribute__((ext_vector_type(8)));

static constexpr float SM_SCALE = 0.08838834764831843f; // 128**-0.5

#define GLOBP(p) (__attribute__((address_space(1))) void*)(p)
#define LDSP(p)  (__attribute__((address_space(3))) void*)(p)
// 16-byte async global->LDS: HW writes lds_base + lane*16; lds_base must be wave-uniform.
#define ASYNC16(g, l) __builtin_amdgcn_global_load_lds(GLOBP(g), LDSP(l), 16, 0, 0)

// ---------------- per-row symmetric int8 quant: int8 out + scale ----------------
__global__ __launch_bounds__(256) void row_quant_k(const float* __restrict__ in,
        signed char* __restrict__ out, float* __restrict__ scale, int cols) {
    int row = blockIdx.x;
    const float4* x4 = (const float4*)(in + (size_t)row * cols);
    unsigned int* op = (unsigned int*)(out + (size_t)row * cols);
    int n4 = cols >> 2;
    int tid = threadIdx.x;
    float amax = 0.f;
    for (int c = tid; c < n4; c += 256) {
        float4 v = x4[c];
        amax = fmaxf(amax, fmaxf(fmaxf(fabsf(v.x), fabsf(v.y)),
                                 fmaxf(fabsf(v.z), fabsf(v.w))));
    }
#pragma unroll
    for (int m = 32; m; m >>= 1) amax = fmaxf(amax, __shfl_xor(amax, m));
    __shared__ float red[4];
    if ((tid & 63) == 0) red[tid >> 6] = amax;
    __syncthreads();
    float a = fmaxf(fmaxf(red[0], red[1]), fmaxf(red[2], red[3]));
    float s = fmaxf(a / 127.0f, 1e-8f);
    if (tid == 0) scale[row] = s;
    for (int c = tid; c < n4; c += 256) {
        float4 v = x4[c];
        int b0 = (int)fminf(fmaxf(rintf(v.x / s), -127.f), 127.f);
        int b1 = (int)fminf(fmaxf(rintf(v.y / s), -127.f), 127.f);
        int b2 = (int)fminf(fmaxf(rintf(v.z / s), -127.f), 127.f);
        int b3 = (int)fminf(fmaxf(rintf(v.w / s), -127.f), 127.f);
        op[c] = (b0 & 255) | ((b1 & 255) << 8) | ((b2 & 255) << 16) | ((b3 & 255) << 24);
    }
}

// ---------------- int8 GEMM: C[m,n] = sa[m]*sb[n]*sum_k qa[m,k]*qb[n,k] ----------------
__global__ __launch_bounds__(256) void gemm_i8_k(const signed char* __restrict__ A,
        const float* __restrict__ sa, const signed char* __restrict__ B,
        const float* __restrict__ sb, float* __restrict__ C, int M, int N, int K) {
    __shared__ __align__(16) signed char lsA[8192];
    __shared__ __align__(16) signed char lsB[8192];
    int tid = threadIdx.x;
    int w = tid >> 6, l = tid & 63;
    int wr = w >> 1, wc = w & 1;
    int lrow = l & 15, lk = (l >> 4) * 16;
    int m0 = blockIdx.y * 128, n0 = blockIdx.x * 128;
    v4i acc[4][4];
#pragma unroll
    for (int i = 0; i < 4; ++i)
#pragma unroll
        for (int j = 0; j < 4; ++j) acc[i][j] = (v4i){0, 0, 0, 0};

    for (int k0 = 0; k0 < K; k0 += 64) {
        __syncthreads();
#pragma unroll
        for (int a = 0; a < 2; ++a) {
            int f = a * 4 + w;
            ASYNC16(A + (size_t)(m0 + f * 16 + lrow) * K + k0 + lk, lsA + f * 1024);
            ASYNC16(B + (size_t)(n0 + f * 16 + lrow) * K + k0 + lk, lsB + f * 1024);
        }
        __syncthreads();
        v4i af[4], bf[4];
#pragma unroll
        for (int i = 0; i < 4; ++i) af[i] = *(const v4i*)(lsA + (wr * 4 + i) * 1024 + l * 16);
#pragma unroll
        for (int j = 0; j < 4; ++j) bf[j] = *(const v4i*)(lsB + (wc * 4 + j) * 1024 + l * 16);
#pragma unroll
        for (int i = 0; i < 4; ++i)
#pragma unroll
            for (int j = 0; j < 4; ++j)
                acc[i][j] = __builtin_amdgcn_mfma_i32_16x16x64_i8(af[i], bf[j], acc[i][j], 0, 0, 0);
    }
    int r0 = m0 + wr * 64, c0 = n0 + wc * 64;
    int lg = l >> 4;
    float sbv[4];
#pragma unroll
    for (int j = 0; j < 4; ++j) sbv[j] = sb[c0 + j * 16 + lrow];
#pragma unroll
    for (int i = 0; i < 4; ++i) {
        float4 s4 = *(const float4*)(sa + r0 + i * 16 + lg * 4);
        float sav[4] = {s4.x, s4.y, s4.z, s4.w};
#pragma unroll
        for (int j = 0; j < 4; ++j) {
#pragma unroll
            for (int reg = 0; reg < 4; ++reg) {
                int r = r0 + i * 16 + lg * 4 + reg;
                C[(size_t)r * N + c0 + j * 16 + lrow] = (float)acc[i][j][reg] * (sav[reg] * sbv[j]);
            }
        }
    }
}

// ---------------- rope inv_freq table (double pow, computed once on device) ----------------
__global__ void rope_init_k(float* __restrict__ inv_tab) {
    int i = threadIdx.x; // 64 threads
    float pw = (float)pow(1.0e6, (double)i / 64.0);
    inv_tab[i] = 1.0f / pw;
}

// ---------------- rmsnorm + rope; q/k -> int8 + scale, v -> dequantized fp32 ----------------
__global__ __launch_bounds__(128) void qkv_post_k(const float* __restrict__ q_lin,
        const float* __restrict__ k_lin, const float* __restrict__ v_lin,
        const float* __restrict__ qw, const float* __restrict__ kw,
        const int* __restrict__ pos_ids, const float* __restrict__ inv_tab,
        signed char* __restrict__ q_i8, float* __restrict__ sq,
        signed char* __restrict__ k_i8, float* __restrict__ sk,
        float* __restrict__ v_dq) {
    int t = blockIdx.x;
    int hh = blockIdx.y;
    int d = threadIdx.x;
    __shared__ float xs[HDIM];
    __shared__ float red[2];
    float x;
    if (hh < NH)            x = q_lin[(size_t)t * DMODEL + hh * HDIM + d];
    else if (hh < NH + NKV) x = k_lin[(size_t)t * (NKV * HDIM) + (hh - NH) * HDIM + d];
    else                    x = v_lin[(size_t)t * (NKV * HDIM) + (hh - NH - NKV) * HDIM + d];

    if (hh < NH + NKV) {
        float sqv = x * x;
#pragma unroll
        for (int m = 32; m; m >>= 1) sqv += __shfl_xor(sqv, m);
        if ((d & 63) == 0) red[d >> 6] = sqv;
        __syncthreads();
        float mv = (red[0] + red[1]) / 128.0f;
        float rs = 1.0f / sqrtf(mv + 1e-6f);
        x = (x * rs) * ((hh < NH) ? qw[d] : kw[d]);
        xs[d] = x;
        __syncthreads();
        float other = (d < 64) ? xs[d + 64] : xs[d - 64];
        int fi = d & 63;
        float inv = inv_tab[fi];
        float fr = (float)pos_ids[t] * inv;
        float sn, c;
        sincosf(fr, &sn, &c);
        x = (d < 64) ? (x * c - other * sn) : (x * c + other * sn);
        __syncthreads();
    }
    float amax = fabsf(x);
#pragma unroll
    for (int m = 32; m; m >>= 1) amax = fmaxf(amax, __shfl_xor(amax, m));
    if ((d & 63) == 0) red[d >> 6] = amax;
    __syncthreads();
    float s = fmaxf(fmaxf(red[0], red[1]) / 127.0f, 1e-8f);
    float qf = fminf(fmaxf(rintf(x / s), -127.f), 127.f);
    if (hh < NH) {
        q_i8[((size_t)hh * SEQ + t) * HDIM + d] = (signed char)(int)qf;
        if (d == 0) sq[hh * SEQ + t] = s;
    } else if (hh < NH + NKV) {
        k_i8[((size_t)(hh - NH) * SEQ + t) * HDIM + d] = (signed char)(int)qf;
        if (d == 0) sk[(hh - NH) * SEQ + t] = s;
    } else {
        v_dq[((size_t)(hh - NH - NKV) * SEQ + t) * HDIM + d] = qf * s;
    }
}

// ---------------- bf16 helpers ----------------
__device__ __forceinline__ unsigned short f2bf(float x) {
    unsigned int u = __float_as_uint(x);
    return (unsigned short)((u + 0x7fffu + ((u >> 16) & 1u)) >> 16);
}
__device__ __forceinline__ float bf2f(unsigned short h) {
    return __uint_as_float(((unsigned int)h) << 16);
}

// ---------------- V transpose + bf16 split ----------------
__global__ __launch_bounds__(256) void vt_split_k(const float* __restrict__ v_dq,
        unsigned short* __restrict__ vt_hi, unsigned short* __restrict__ vt_lo) {
    int kv = blockIdx.y, t0 = blockIdx.x * 64;
    __shared__ float tile[64][132];
    int tid = threadIdx.x;
    const float* src = v_dq + ((size_t)kv * SEQ + t0) * HDIM;
#pragma unroll
    for (int i = 0; i < 8; ++i) {
        int f4 = i * 256 + tid;
        int r = f4 >> 5, c = (f4 & 31) << 2;
        float4 v = *(const float4*)(src + r * HDIM + c);
        tile[r][c] = v.x; tile[r][c + 1] = v.y; tile[r][c + 2] = v.z; tile[r][c + 3] = v.w;
    }
    __syncthreads();
    int d = tid >> 1, th = (tid & 1) * 32;
    size_t obase = ((size_t)kv * HDIM + d) * SEQ + t0 + th;
#pragma unroll
    for (int j = 0; j < 32; j += 2) {
        float a = tile[th + j][d], b = tile[th + j + 1][d];
        unsigned short ah = f2bf(a), bh = f2bf(b);
        unsigned short al = f2bf(a - bf2f(ah)), bl = f2bf(b - bf2f(bh));
        *(unsigned int*)(vt_hi + obase + j) = (unsigned int)ah | ((unsigned int)bh << 16);
        *(unsigned int*)(vt_lo + obase + j) = (unsigned int)al | ((unsigned int)bl << 16);
    }
}

// ---------------- attention v2 ----------------
// Pass 1 barrier-free: K fragments global->registers, explicit 2-deep dbuf.
// Pass 2: K->regs (dbuf), V->LDS via ASYNC16 double-buffered, ONE vmcnt(0)+barrier per kb.
// plds is wave-private (no barrier). Heaviest q-tiles dispatched first (qb reversed).
__global__ __launch_bounds__(256, 2) void attn_k(const signed char* __restrict__ q_i8,
        const float* __restrict__ sq, const signed char* __restrict__ k_i8,
        const float* __restrict__ sk, const unsigned short* __restrict__ vt_hi,
        const unsigned short* __restrict__ vt_lo, float* __restrict__ attn2) {
    __shared__ __align__(16) unsigned short vlds[2][16384]; // 32 KB each buf
    __shared__ __align__(16) unsigned short plds[4096];     // 8 KB, wave-private regions
    int qb = 31 - blockIdx.x;           // heavy tiles first
    int h = blockIdx.y, kvh = h >> 1;
    int q0 = qb * 64;
    int tid = threadIdx.x, w = tid >> 6, l = tid & 63;
    int lrow = l & 15, lg = l >> 4;

    const signed char* qrow = q_i8 + ((size_t)h * SEQ + q0 + w * 16 + lrow) * HDIM + lg * 16;
    v4i qf0 = *(const v4i*)(qrow);
    v4i qf1 = *(const v4i*)(qrow + 64);
    float4 s4 = *(const float4*)(sq + (size_t)h * SEQ + q0 + w * 16 + lg * 4);
    float sqr[4] = {s4.x, s4.y, s4.z, s4.w};

    float m_run[4], z_run[4];
#pragma unroll
    for (int r = 0; r < 4; ++r) { m_run[r] = -1e30f; z_run[r] = 0.f; }

    int nkb = qb + 1;
    const signed char* kbase = k_i8 + (size_t)kvh * SEQ * HDIM;
    const float* skb = sk + (size_t)kvh * SEQ;
    const unsigned short* vhb = vt_hi + (size_t)kvh * HDIM * SEQ;
    const unsigned short* vlb = vt_lo + (size_t)kvh * HDIM * SEQ;

    v4i ka[8], kn[8];
    auto loadK = [&](v4i* dst, int k0) {
#pragma unroll
        for (int f = 0; f < 8; ++f) {
            int j = f >> 1, kk = f & 1;
            dst[f] = *(const v4i*)(kbase + (size_t)(k0 + j * 16 + lrow) * HDIM + kk * 64 + lg * 16);
        }
    };
    auto issueV = [&](int kb) {
        int k0 = kb * 64;
        unsigned short* vb = &vlds[kb & 1][0];
#pragma unroll
        for (int a = 0; a < 8; ++a) {
            int fv = a * 4 + w;
            int sp_ = fv >> 4, jd = (fv >> 1) & 7, kk2 = fv & 1;
            const unsigned short* vsrc = (sp_ ? vlb : vhb) +
                (size_t)(jd * 16 + lrow) * SEQ + k0 + kk2 * 32 + lg * 8;
            ASYNC16(vsrc, vb + fv * 512);
        }
    };

    // ================= pass 1: running max + Z (barrier-free) =================
    loadK(ka, 0);
    for (int kb = 0; kb < nkb; ++kb) {
        if (kb + 1 < nkb) loadK(kn, (kb + 1) * 64);
        int k0 = kb * 64;
        v4i sci[4];
#pragma unroll
        for (int j = 0; j < 4; ++j) {
            v4i z = {0, 0, 0, 0};
            v4i t0 = __builtin_amdgcn_mfma_i32_16x16x64_i8(qf0, ka[j * 2], z, 0, 0, 0);
            sci[j] = __builtin_amdgcn_mfma_i32_16x16x64_i8(qf1, ka[j * 2 + 1], t0, 0, 0, 0);
        }
        float skc[4];
#pragma unroll
        for (int j = 0; j < 4; ++j) skc[j] = skb[k0 + j * 16 + lrow];
#pragma unroll
        for (int reg = 0; reg < 4; ++reg) {
            int r = q0 + w * 16 + lg * 4 + reg;
            float s[4];
#pragma unroll
            for (int j = 0; j < 4; ++j) {
                float sv = ((float)sci[j][reg] * (sqr[reg] * skc[j])) * SM_SCALE;
                s[j] = (k0 + j * 16 + lrow <= r) ? sv : -1e30f;
            }
            float mt = fmaxf(fmaxf(s[0], s[1]), fmaxf(s[2], s[3]));
#pragma unroll
            for (int m = 1; m <= 8; m <<= 1) mt = fmaxf(mt, __shfl_xor(mt, m));
            float mn = fmaxf(m_run[reg], mt);
            float zt = 0.f;
#pragma unroll
            for (int j = 0; j < 4; ++j) zt += __expf(s[j] - mn);
#pragma unroll
            for (int m = 1; m <= 8; m <<= 1) zt += __shfl_xor(zt, m);
            z_run[reg] = z_run[reg] * __expf(m_run[reg] - mn) + zt;
            m_run[reg] = mn;
        }
        if (kb + 1 < nkb) {
#pragma unroll
            for (int f = 0; f < 8; ++f) ka[f] = kn[f];
        }
    }

    float zinv[4], spv[4], rsp[4];
#pragma unroll
    for (int r = 0; r < 4; ++r) {
        zinv[r] = 1.0f / z_run[r];               // = ref's max softmax element fl(1/Z)
        spv[r] = fmaxf(zinv[r] / 127.0f, 1e-8f);
        rsp[r] = 1.0f / spv[r];
    }

    v4f acco[8];
#pragma unroll
    for (int jd = 0; jd < 8; ++jd) acco[jd] = (v4f){0.f, 0.f, 0.f, 0.f};

    // ================= pass 2: scores -> quantized p -> PV =================
    loadK(ka, 0);
    issueV(0);
    asm volatile("s_waitcnt vmcnt(0)" ::: "memory");
    __syncthreads();
    for (int kb = 0; kb < nkb; ++kb) {
        int k0 = kb * 64;
        // issue next tile's loads early (overlap with this tile's compute)
        if (kb + 1 < nkb) {
            issueV(kb + 1);
            loadK(kn, (kb + 1) * 64);
        }
        v4i sci[4];
#pragma unroll
        for (int j = 0; j < 4; ++j) {
            v4i z = {0, 0, 0, 0};
            v4i t0 = __builtin_amdgcn_mfma_i32_16x16x64_i8(qf0, ka[j * 2], z, 0, 0, 0);
            sci[j] = __builtin_amdgcn_mfma_i32_16x16x64_i8(qf1, ka[j * 2 + 1], t0, 0, 0, 0);
        }
        float skc[4];
#pragma unroll
        for (int j = 0; j < 4; ++j) skc[j] = skb[k0 + j * 16 + lrow];
#pragma unroll
        for (int reg = 0; reg < 4; ++reg) {
            int rq = lg * 4 + reg;
            int r = q0 + w * 16 + rq;
#pragma unroll
            for (int j = 0; j < 4; ++j) {
                int c = j * 16 + lrow;
                float pd = 0.f;
                if (k0 + c <= r) {
                    float sv = ((float)sci[j][reg] * (sqr[reg] * skc[j])) * SM_SCALE;
                    float p = __expf(sv - m_run[reg]) * zinv[reg];
                    pd = fminf(rintf(p * rsp[reg]), 127.f);   // int value of quantized p
                }
                plds[(w * 2 + (c >> 5)) * 512 + (rq + 16 * ((c >> 3) & 3)) * 8 + (c & 7)] =
                    (unsigned short)(__float_as_uint(pd) >> 16);  // exact bf16 of small int
            }
        }
        // plds region is wave-private: only need LDS-op completion, no barrier
        v8bf pf0 = *(const v8bf*)(plds + (w * 2 + 0) * 512 + l * 8);
        v8bf pf1 = *(const v8bf*)(plds + (w * 2 + 1) * 512 + l * 8);
        const unsigned short* vb = &vlds[kb & 1][0];
#pragma unroll
        for (int jd = 0; jd < 8; ++jd) {
            v8bf vh0 = *(const v8bf*)(vb + (jd * 2 + 0) * 512 + l * 8);
            v8bf vh1 = *(const v8bf*)(vb + (jd * 2 + 1) * 512 + l * 8);
            v8bf vl0 = *(const v8bf*)(vb + (16 + jd * 2 + 0) * 512 + l * 8);
            v8bf vl1 = *(const v8bf*)(vb + (16 + jd * 2 + 1) * 512 + l * 8);
            v4f t = acco[jd];
            t = __builtin_amdgcn_mfma_f32_16x16x32_bf16(pf0, vh0, t, 0, 0, 0);
            t = __builtin_amdgcn_mfma_f32_16x16x32_bf16(pf1, vh1, t, 0, 0, 0);
            t = __builtin_amdgcn_mfma_f32_16x16x32_bf16(pf0, vl0, t, 0, 0, 0);
            t = __builtin_amdgcn_mfma_f32_16x16x32_bf16(pf1, vl1, t, 0, 0, 0);
            acco[jd] = t;
        }
        // drain next-tile ASYNC16 (and K prefetch), then block-sync: buffer swap safe
        asm volatile("s_waitcnt vmcnt(0)" ::: "memory");
        __syncthreads();
        if (kb + 1 < nkb) {
#pragma unroll
            for (int f = 0; f < 8; ++f) ka[f] = kn[f];
        }
    }
#pragma unroll
    for (int jd = 0; jd < 8; ++jd) {
#pragma unroll
        for (int reg = 0; reg < 4; ++reg) {
            int r = q0 + w * 16 + lg * 4 + reg;
            attn2[(size_t)r * DMODEL + h * HDIM + jd * 16 + lrow] = acco[jd][reg] * spv[reg];
        }
    }
}

extern "C" void kernel_launch(void* const* d_in, const int* in_sizes, int n_in,
                              void* d_out, int out_size, void* d_ws, size_t ws_size,
                              hipStream_t stream) {
    (void)in_sizes; (void)n_in; (void)out_size; (void)ws_size;
    const float* hidden = (const float*)d_in[0];
    const float* Wq = (const float*)d_in[1];
    const float* Wk = (const float*)d_in[2];
    const float* Wv = (const float*)d_in[3];
    const float* Wo = (const float*)d_in[4];
    const float* qw = (const float*)d_in[5];
    const float* kw = (const float*)d_in[6];
    const int* pos = (const int*)d_in[7];
    float* out = (float*)d_out;
    char* ws = (char*)d_ws;

    const size_t MB = 1024 * 1024;
    signed char* x_i8  = (signed char*)(ws);            // 4 MB
    signed char* wq_i8 = (signed char*)(ws + 4 * MB);   // 4 MB
    signed char* wk_i8 = (signed char*)(ws + 8 * MB);   // 2 MB
    signed char* wv_i8 = (signed char*)(ws + 10 * MB);  // 2 MB
    signed char* wo_i8 = (signed char*)(ws + 12 * MB);  // 4 MB
    signed char* q_i8  = (signed char*)(ws + 16 * MB);  // 4 MB
    signed char* k_i8  = (signed char*)(ws + 20 * MB);  // 2 MB
    float* sx  = (float*)(ws + 22 * MB);                // scales block
    float* swq = sx + 2048;
    float* swk = swq + 2048;
    float* swv = swk + 1024;
    float* swo = swv + 1024;
    float* sq  = swo + 2048;                            // 16*2048
    float* sk  = sq + NH * SEQ;                         // 8*2048
    float* sa  = sk + NKV * SEQ;                        // 2048
    float* inv_tab = sa + 2048;                         // 64 floats
    float* q_lin = (float*)(ws + 24 * MB);              // 16 MB
    float* k_lin = (float*)(ws + 40 * MB);              // 8 MB
    float* v_lin = (float*)(ws + 48 * MB);              // 8 MB (dead after qkv_post)
    unsigned short* vt_hi = (unsigned short*)(ws + 48 * MB);       // 4 MB (aliases v_lin)
    unsigned short* vt_lo = (unsigned short*)(ws + 52 * MB);       // 4 MB
    float* v_dq = (float*)(ws + 56 * MB);               // 8 MB
    float* attn2 = q_lin;                               // q_lin dead after qkv_post
    signed char* a_i8 = x_i8;                           // x_i8 dead after QKV GEMMs

    rope_init_k<<<1, 64, 0, stream>>>(inv_tab);
    row_quant_k<<<2048, 256, 0, stream>>>(hidden, x_i8, sx, 2048);
    row_quant_k<<<2048, 256, 0, stream>>>(Wq, wq_i8, swq, 2048);
    row_quant_k<<<1024, 256, 0, stream>>>(Wk, wk_i8, swk, 2048);
    row_quant_k<<<1024, 256, 0, stream>>>(Wv, wv_i8, swv, 2048);
    row_quant_k<<<2048, 256, 0, stream>>>(Wo, wo_i8, swo, 2048);

    gemm_i8_k<<<dim3(16, 16), 256, 0, stream>>>(x_i8, sx, wq_i8, swq, q_lin, 2048, 2048, 2048);
    gemm_i8_k<<<dim3(8, 16), 256, 0, stream>>>(x_i8, sx, wk_i8, swk, k_lin, 2048, 1024, 2048);
    gemm_i8_k<<<dim3(8, 16), 256, 0, stream>>>(x_i8, sx, wv_i8, swv, v_lin, 2048, 1024, 2048);

    qkv_post_k<<<dim3(2048, 32), 128, 0, stream>>>(q_lin, k_lin, v_lin, qw, kw, pos, inv_tab,
                                                   q_i8, sq, k_i8, sk, v_dq);
    vt_split_k<<<dim3(32, 8), 256, 0, stream>>>(v_dq, vt_hi, vt_lo);

    attn_k<<<dim3(32, 16), 256, 0, stream>>>(q_i8, sq, k_i8, sk, vt_hi, vt_lo, attn2);

    row_quant_k<<<2048, 256, 0, stream>>>(attn2, a_i8, sa, 2048);
    gemm_i8_k<<<dim3(16, 16), 256, 0, stream>>>(a_i8, sa, wo_i8, swo, out, 2048, 2048, 2048);
}